// Round 1
// baseline (52366.846 us; speedup 1.0000x reference)
//
#include <hip/hip_runtime.h>
#include <math.h>

#define Bp 64
#define Sp 512
#define Ep 128
#define Hp 1024
#define Vp 128
#define Op 128

// ws layout (floats):
//   XV : Vp*3*Hp            = 393216     (x-side projections per vocab id, incl. input biases)
//   WT : 3*Hp*Hp            = 3145728    (Whr|Whz|Whn transposed to [g][j][k], k-contiguous)
//   ys : Sp*Bp*Hp           = 33554432   (all hidden states, [s][b][h])
#define WS_XV   0
#define WS_WT   (Vp*3*Hp)
#define WS_YS   (WS_WT + 3*Hp*Hp)
#define WS_FLOATS (WS_YS + (size_t)Sp*Bp*Hp)

// ---------------------------------------------------------------- XV precompute
// XV[v][g*H + j] = b_g[j] + sum_e emb[v][e] * W_g[e][j]
__global__ __launch_bounds__(256) void xv_kernel(
    const float* __restrict__ emb,
    const float* __restrict__ Wir, const float* __restrict__ bir,
    const float* __restrict__ Wiz, const float* __restrict__ biz,
    const float* __restrict__ Win, const float* __restrict__ bin_,
    float* __restrict__ XV) {
  int n = blockIdx.x * 256 + threadIdx.x;   // 0..3071
  int v = blockIdx.y;                        // 0..127
  int g = n >> 10;
  int j = n & (Hp - 1);
  const float* W = (g == 0) ? Wir : ((g == 1) ? Wiz : Win);
  const float* bias = (g == 0) ? bir : ((g == 1) ? biz : bin_);
  float acc = bias[j];
  const float* ev = emb + (size_t)v * Ep;
  for (int e = 0; e < Ep; ++e) acc += ev[e] * W[(size_t)e * Hp + j];
  XV[(size_t)v * (3 * Hp) + n] = acc;
}

// ---------------------------------------------------------------- W transpose
// WT[g][j][k] = W_g[k][j]
__global__ void wt_kernel(const float* __restrict__ Whr,
                          const float* __restrict__ Whz,
                          const float* __restrict__ Whn,
                          float* __restrict__ WT) {
  __shared__ float tile[32][33];
  int g = blockIdx.z;
  const float* src = (g == 0) ? Whr : ((g == 1) ? Whz : Whn);
  int kb = blockIdx.x * 32;
  int jb = blockIdx.y * 32;
  int tx = threadIdx.x, ty = threadIdx.y;  // 32 x 8
  #pragma unroll
  for (int i = 0; i < 4; ++i)
    tile[ty + 8 * i][tx] = src[(size_t)(kb + ty + 8 * i) * Hp + (jb + tx)];
  __syncthreads();
  #pragma unroll
  for (int i = 0; i < 4; ++i)
    WT[(size_t)g * Hp * Hp + (size_t)(jb + ty + 8 * i) * Hp + (kb + tx)] =
        tile[tx][ty + 8 * i];
}

// ---------------------------------------------------------------- GRU step
// One launch per timestep. Grid: 256 blocks (4 h-cols each) x 256 threads.
// thread t -> b = t>>2, c = t&3; computes r/z/n dots (K=1024) for (b, j).
__global__ __launch_bounds__(256) void gru_step(
    const float* __restrict__ h_prev,   // [B][H]
    float* __restrict__ h_out,          // [B][H]  (= ys[t])
    const float* __restrict__ WT,       // [3][H][H]
    const float* __restrict__ XV,       // [V][3H]
    const int* __restrict__ toks,       // [B][S]
    const float* __restrict__ bhn,      // [H]
    int t) {
  int tid = threadIdx.x;
  int b = tid >> 2;
  int c = tid & 3;
  int j = blockIdx.x * 4 + c;

  const float4* hp = (const float4*)(h_prev + (size_t)b * Hp);
  const float4* wr = (const float4*)(WT + ((size_t)0 * Hp + j) * Hp);
  const float4* wz = (const float4*)(WT + ((size_t)1 * Hp + j) * Hp);
  const float4* wn = (const float4*)(WT + ((size_t)2 * Hp + j) * Hp);

  float ar = 0.f, az = 0.f, an = 0.f;
  #pragma unroll 4
  for (int kk = 0; kk < Hp / 4; ++kk) {
    float4 h4 = hp[kk];
    float4 r4 = wr[kk];
    float4 z4 = wz[kk];
    float4 n4 = wn[kk];
    ar += h4.x * r4.x + h4.y * r4.y + h4.z * r4.z + h4.w * r4.w;
    az += h4.x * z4.x + h4.y * z4.y + h4.z * z4.z + h4.w * z4.w;
    an += h4.x * n4.x + h4.y * n4.y + h4.z * n4.z + h4.w * n4.w;
  }

  int tok = toks[b * Sp + t];
  const float* xv = XV + (size_t)tok * (3 * Hp);
  float xr = xv[j];
  float xz = xv[Hp + j];
  float xn = xv[2 * Hp + j];

  float r = 1.f / (1.f + expf(-(ar + xr)));
  float z = 1.f / (1.f + expf(-(az + xz)));
  float n = tanhf(xn + r * (an + bhn[j]));
  float hold = h_prev[(size_t)b * Hp + j];
  h_out[(size_t)b * Hp + j] = (1.f - z) * n + z * hold;
}

// ---------------------------------------------------------------- fused output denses
// block = 16 output rows (r = b*S + s); hidden kept in LDS, never in HBM.
__global__ __launch_bounds__(256) void dense_kernel(
    const float* __restrict__ ys,   // [S][B][H]
    const float* __restrict__ Wh, const float* __restrict__ bh,
    const float* __restrict__ Wo, const float* __restrict__ bo,
    float* __restrict__ out) {      // logits at out + B*H
  __shared__ float hs[16][1032];
  __shared__ float hid[16][1032];
  int tid = threadIdx.x;
  int r0 = blockIdx.x * 16;
  int bq = r0 / Sp;        // constant within tile (S % 16 == 0)
  int s0 = r0 % Sp;

  // stage 16 rows of h states
  for (int i = tid; i < 16 * 256; i += 256) {
    int m = i >> 8;
    int f = i & 255;
    float4 v = ((const float4*)(ys + (size_t)(s0 + m) * (Bp * Hp) + (size_t)bq * Hp))[f];
    ((float4*)&hs[m][0])[f] = v;
  }
  __syncthreads();

  // hidden = hs @ Wh + bh   (thread t owns cols 4t..4t+3)
  float4 acc[16];
  float4 bh4 = ((const float4*)bh)[tid];
  #pragma unroll
  for (int m = 0; m < 16; ++m) acc[m] = bh4;
  for (int k = 0; k < Hp; ++k) {
    float4 w = ((const float4*)(Wh + (size_t)k * Hp))[tid];
    #pragma unroll
    for (int m = 0; m < 16; ++m) {
      float hv = hs[m][k];
      acc[m].x += hv * w.x;
      acc[m].y += hv * w.y;
      acc[m].z += hv * w.z;
      acc[m].w += hv * w.w;
    }
  }
  #pragma unroll
  for (int m = 0; m < 16; ++m) ((float4*)&hid[m][0])[tid] = acc[m];
  __syncthreads();

  // logits = hid @ Wo + bo  (thread t: o = t&127, half = t>>7 -> 8 rows)
  int o = tid & (Op - 1);
  int half = tid >> 7;
  float lacc[8];
  float bov = bo[o];
  #pragma unroll
  for (int mm = 0; mm < 8; ++mm) lacc[mm] = bov;
  for (int k = 0; k < Hp; ++k) {
    float wo = Wo[(size_t)k * Op + o];
    #pragma unroll
    for (int mm = 0; mm < 8; ++mm) lacc[mm] += hid[half * 8 + mm][k] * wo;
  }
  float* lo = out + (size_t)Bp * Hp;
  #pragma unroll
  for (int mm = 0; mm < 8; ++mm) {
    int r = r0 + half * 8 + mm;
    lo[(size_t)r * Op + o] = lacc[mm];
  }
}

// ---------------------------------------------------------------- carry out
__global__ void carry_kernel(const float* __restrict__ ys, float* __restrict__ out) {
  int i = blockIdx.x * 256 + threadIdx.x;
  out[i] = ys[(size_t)(Sp - 1) * (Bp * Hp) + i];
}

extern "C" void kernel_launch(void* const* d_in, const int* in_sizes, int n_in,
                              void* d_out, int out_size, void* d_ws, size_t ws_size,
                              hipStream_t stream) {
  const int*   toks = (const int*)  d_in[0];
  const float* carry= (const float*)d_in[1];
  const float* emb  = (const float*)d_in[2];
  const float* Wir  = (const float*)d_in[3];
  const float* bir  = (const float*)d_in[4];
  const float* Whr  = (const float*)d_in[5];
  const float* Wiz  = (const float*)d_in[6];
  const float* biz  = (const float*)d_in[7];
  const float* Whz  = (const float*)d_in[8];
  const float* Win  = (const float*)d_in[9];
  const float* bin_ = (const float*)d_in[10];
  const float* Whn  = (const float*)d_in[11];
  const float* bhn  = (const float*)d_in[12];
  const float* Wh   = (const float*)d_in[13];
  const float* bh   = (const float*)d_in[14];
  const float* Wo   = (const float*)d_in[15];
  const float* bo   = (const float*)d_in[16];
  float* out = (float*)d_out;

  if (ws_size < WS_FLOATS * sizeof(float)) return;  // workspace too small -> fail loudly

  float* ws = (float*)d_ws;
  float* XV = ws + WS_XV;
  float* WT = ws + WS_WT;
  float* ys = ws + WS_YS;

  // preps
  xv_kernel<<<dim3(12, Vp), 256, 0, stream>>>(emb, Wir, bir, Wiz, biz, Win, bin_, XV);
  wt_kernel<<<dim3(Hp / 32, Hp / 32, 3), dim3(32, 8), 0, stream>>>(Whr, Whz, Whn, WT);

  // sequential GRU scan: 512 launches, h state lives in ys rows
  const float* hp = carry;
  for (int t = 0; t < Sp; ++t) {
    float* ho = ys + (size_t)t * (Bp * Hp);
    gru_step<<<256, 256, 0, stream>>>(hp, ho, WT, XV, toks, bhn, t);
    hp = ho;
  }

  // outputs
  carry_kernel<<<(Bp * Hp) / 256, 256, 0, stream>>>(ys, out);
  dense_kernel<<<(Bp * Sp) / 16, 256, 0, stream>>>(ys, Wh, bh, Wo, bo, out);
}

// Round 2
// 28009.351 us; speedup vs baseline: 1.8696x; 1.8696x over previous
//
#include <hip/hip_runtime.h>
#include <hip/hip_cooperative_groups.h>
#include <math.h>

namespace cg = cooperative_groups;

#define Bp 64
#define Sp 512
#define Ep 128
#define Hp 1024
#define Vp 128
#define Op 128

// ws layout (floats):
//   XV : Vp*3*Hp   (x-side projections per vocab id, incl. input biases)
//   WT : 3*Hp*Hp   (Whr|Whz|Whn transposed to [g][j][k], k-contiguous)
//   ys : Sp*Bp*Hp  (all hidden states, [s][b][h])
#define WS_XV   0
#define WS_WT   (Vp*3*Hp)
#define WS_YS   (WS_WT + 3*Hp*Hp)
#define WS_FLOATS (WS_YS + (size_t)Sp*Bp*Hp)

// ---------------------------------------------------------------- XV precompute
// XV[v][g*H + j] = b_g[j] + sum_e emb[v][e] * W_g[e][j]
__global__ __launch_bounds__(256) void xv_kernel(
    const float* __restrict__ emb,
    const float* __restrict__ Wir, const float* __restrict__ bir,
    const float* __restrict__ Wiz, const float* __restrict__ biz,
    const float* __restrict__ Win, const float* __restrict__ bin_,
    float* __restrict__ XV) {
  int n = blockIdx.x * 256 + threadIdx.x;   // 0..3071
  int v = blockIdx.y;                        // 0..127
  int g = n >> 10;
  int j = n & (Hp - 1);
  const float* W = (g == 0) ? Wir : ((g == 1) ? Wiz : Win);
  const float* bias = (g == 0) ? bir : ((g == 1) ? biz : bin_);
  float acc = bias[j];
  const float* ev = emb + (size_t)v * Ep;
  for (int e = 0; e < Ep; ++e) acc += ev[e] * W[(size_t)e * Hp + j];
  XV[(size_t)v * (3 * Hp) + n] = acc;
}

// ---------------------------------------------------------------- W transpose
// WT[g][j][k] = W_g[k][j]
__global__ void wt_kernel(const float* __restrict__ Whr,
                          const float* __restrict__ Whz,
                          const float* __restrict__ Whn,
                          float* __restrict__ WT) {
  __shared__ float tile[32][33];
  int g = blockIdx.z;
  const float* src = (g == 0) ? Whr : ((g == 1) ? Whz : Whn);
  int kb = blockIdx.x * 32;
  int jb = blockIdx.y * 32;
  int tx = threadIdx.x, ty = threadIdx.y;  // 32 x 8
  #pragma unroll
  for (int i = 0; i < 4; ++i)
    tile[ty + 8 * i][tx] = src[(size_t)(kb + ty + 8 * i) * Hp + (jb + tx)];
  __syncthreads();
  #pragma unroll
  for (int i = 0; i < 4; ++i)
    WT[(size_t)g * Hp * Hp + (size_t)(jb + ty + 8 * i) * Hp + (kb + tx)] =
        tile[tx][ty + 8 * i];
}

// ---------------------------------------------------------------- persistent GRU scan
// 256 blocks (1/CU) x 256 threads, cooperative. Block owns j-slice of 4 cols
// (all 3 gates, all 64 batches). Weights + XV slice live in LDS for all 512
// steps. grid.sync() between steps.
#define JB 4
#define WROW 1028   // 1024 + 4 pad: c-stride banks = c*4 % 32 -> disjoint bank quads

__global__ __launch_bounds__(256, 1) void gru_scan(
    const float* __restrict__ carry,   // [B][H] initial h
    float* __restrict__ ys,            // [S][B][H]
    const float* __restrict__ WT,      // [3][H][H] k-contiguous
    const float* __restrict__ XV,      // [V][3H]
    const int* __restrict__ toks,      // [B][S]
    const float* __restrict__ bhn) {   // [H]
  __shared__ float wlds[3 * JB * WROW];   // 49,344 B
  __shared__ float xvl[Vp * 3 * JB];      // 6,144 B
  __shared__ float bhn_s[JB];

  cg::grid_group grid = cg::this_grid();

  const int tid = threadIdx.x;
  const int jb = blockIdx.x * JB;

  // ---- one-time LDS staging ----
  // weights: wlds[(g*JB + c)*WROW + k] = WT[(g*H + jb + c)*H + k], float4 coalesced
  for (int i = tid; i < 3 * JB * (Hp / 4); i += 256) {
    int g = i >> 10;              // /(JB*256)
    int c = (i >> 8) & (JB - 1);
    int k4 = i & 255;
    float4 v = ((const float4*)WT)[((size_t)g * Hp + jb + c) * (Hp / 4) + k4];
    ((float4*)&wlds[(g * JB + c) * WROW])[k4] = v;
  }
  // xv slice: xvl[v*12 + g*4 + c] = XV[v*3072 + g*1024 + jb + c]
  for (int i = tid; i < Vp * 3 * JB; i += 256) {
    int v = i / (3 * JB);
    int r = i - v * (3 * JB);
    int g = r >> 2;
    int c = r & 3;
    xvl[i] = XV[(size_t)v * (3 * Hp) + g * Hp + jb + c];
  }
  if (tid < JB) bhn_s[tid] = bhn[jb + tid];
  __syncthreads();

  const int b = tid >> 2;
  const int c = tid & 3;
  const int j = jb + c;
  const float4* wr4 = (const float4*)&wlds[(0 * JB + c) * WROW];
  const float4* wz4 = (const float4*)&wlds[(1 * JB + c) * WROW];
  const float4* wn4 = (const float4*)&wlds[(2 * JB + c) * WROW];
  const float bhnv = bhn_s[c];

  const float* hp = carry;
  for (int t = 0; t < Sp; ++t) {
    const float4* h4p = (const float4*)(hp + (size_t)b * Hp);
    float ar = 0.f, az = 0.f, an = 0.f;
    #pragma unroll 4
    for (int kk = 0; kk < Hp / 4; ++kk) {
      float4 h4 = h4p[kk];
      float4 r4 = wr4[kk];
      float4 z4 = wz4[kk];
      float4 n4 = wn4[kk];
      ar += h4.x * r4.x + h4.y * r4.y + h4.z * r4.z + h4.w * r4.w;
      az += h4.x * z4.x + h4.y * z4.y + h4.z * z4.z + h4.w * z4.w;
      an += h4.x * n4.x + h4.y * n4.y + h4.z * n4.z + h4.w * n4.w;
    }

    int tok = toks[b * Sp + t];
    float xr = xvl[tok * (3 * JB) + c];
    float xz = xvl[tok * (3 * JB) + JB + c];
    float xn = xvl[tok * (3 * JB) + 2 * JB + c];

    float r = 1.f / (1.f + expf(-(ar + xr)));
    float z = 1.f / (1.f + expf(-(az + xz)));
    float n = tanhf(xn + r * (an + bhnv));
    float hold = hp[(size_t)b * Hp + j];

    float* ho = ys + (size_t)t * (Bp * Hp);
    ho[(size_t)b * Hp + j] = (1.f - z) * n + z * hold;

    hp = ho;
    grid.sync();
  }
}

// ---------------------------------------------------------------- fused output denses
__global__ __launch_bounds__(256) void dense_kernel(
    const float* __restrict__ ys,   // [S][B][H]
    const float* __restrict__ Wh, const float* __restrict__ bh,
    const float* __restrict__ Wo, const float* __restrict__ bo,
    float* __restrict__ out) {      // logits at out + B*H
  __shared__ float hs[16][1032];
  __shared__ float hid[16][1032];
  int tid = threadIdx.x;
  int r0 = blockIdx.x * 16;
  int bq = r0 / Sp;        // constant within tile (S % 16 == 0)
  int s0 = r0 % Sp;

  for (int i = tid; i < 16 * 256; i += 256) {
    int m = i >> 8;
    int f = i & 255;
    float4 v = ((const float4*)(ys + (size_t)(s0 + m) * (Bp * Hp) + (size_t)bq * Hp))[f];
    ((float4*)&hs[m][0])[f] = v;
  }
  __syncthreads();

  float4 acc[16];
  float4 bh4 = ((const float4*)bh)[tid];
  #pragma unroll
  for (int m = 0; m < 16; ++m) acc[m] = bh4;
  for (int k = 0; k < Hp; ++k) {
    float4 w = ((const float4*)(Wh + (size_t)k * Hp))[tid];
    #pragma unroll
    for (int m = 0; m < 16; ++m) {
      float hv = hs[m][k];
      acc[m].x += hv * w.x;
      acc[m].y += hv * w.y;
      acc[m].z += hv * w.z;
      acc[m].w += hv * w.w;
    }
  }
  #pragma unroll
  for (int m = 0; m < 16; ++m) ((float4*)&hid[m][0])[tid] = acc[m];
  __syncthreads();

  int o = tid & (Op - 1);
  int half = tid >> 7;
  float lacc[8];
  float bov = bo[o];
  #pragma unroll
  for (int mm = 0; mm < 8; ++mm) lacc[mm] = bov;
  for (int k = 0; k < Hp; ++k) {
    float wo = Wo[(size_t)k * Op + o];
    #pragma unroll
    for (int mm = 0; mm < 8; ++mm) lacc[mm] += hid[half * 8 + mm][k] * wo;
  }
  float* lo = out + (size_t)Bp * Hp;
  #pragma unroll
  for (int mm = 0; mm < 8; ++mm) {
    int r = r0 + half * 8 + mm;
    lo[(size_t)r * Op + o] = lacc[mm];
  }
}

// ---------------------------------------------------------------- carry out
__global__ void carry_kernel(const float* __restrict__ ys, float* __restrict__ out) {
  int i = blockIdx.x * 256 + threadIdx.x;
  out[i] = ys[(size_t)(Sp - 1) * (Bp * Hp) + i];
}

extern "C" void kernel_launch(void* const* d_in, const int* in_sizes, int n_in,
                              void* d_out, int out_size, void* d_ws, size_t ws_size,
                              hipStream_t stream) {
  const int*   toks = (const int*)  d_in[0];
  const float* carry= (const float*)d_in[1];
  const float* emb  = (const float*)d_in[2];
  const float* Wir  = (const float*)d_in[3];
  const float* bir  = (const float*)d_in[4];
  const float* Whr  = (const float*)d_in[5];
  const float* Wiz  = (const float*)d_in[6];
  const float* biz  = (const float*)d_in[7];
  const float* Whz  = (const float*)d_in[8];
  const float* Win  = (const float*)d_in[9];
  const float* bin_ = (const float*)d_in[10];
  const float* Whn  = (const float*)d_in[11];
  const float* bhn  = (const float*)d_in[12];
  const float* Wh   = (const float*)d_in[13];
  const float* bh   = (const float*)d_in[14];
  const float* Wo   = (const float*)d_in[15];
  const float* bo   = (const float*)d_in[16];
  float* out = (float*)d_out;

  if (ws_size < WS_FLOATS * sizeof(float)) return;

  float* ws = (float*)d_ws;
  float* XV = ws + WS_XV;
  float* WT = ws + WS_WT;
  float* ys = ws + WS_YS;

  // preps
  xv_kernel<<<dim3(12, Vp), 256, 0, stream>>>(emb, Wir, bir, Wiz, biz, Win, bin_, XV);
  wt_kernel<<<dim3(Hp / 32, Hp / 32, 3), dim3(32, 8), 0, stream>>>(Whr, Whz, Whn, WT);

  // persistent cooperative scan
  {
    void* args[] = {(void*)&carry, (void*)&ys, (void*)&WT, (void*)&XV,
                    (void*)&toks, (void*)&bhn};
    hipLaunchCooperativeKernel((const void*)gru_scan, dim3(256), dim3(256),
                               args, 0, stream);
  }

  // outputs
  carry_kernel<<<(Bp * Hp) / 256, 256, 0, stream>>>(ys, out);
  dense_kernel<<<(Bp * Sp) / 16, 256, 0, stream>>>(ys, Wh, bh, Wo, bo, out);
}

// Round 4
// 19189.000 us; speedup vs baseline: 2.7290x; 1.4597x over previous
//
#include <hip/hip_runtime.h>
#include <hip/hip_cooperative_groups.h>
#include <math.h>

namespace cg = cooperative_groups;

#define Bp 64
#define Sp 512
#define Ep 128
#define Hp 1024
#define Vp 128
#define Op 128

typedef short s8v __attribute__((ext_vector_type(8)));
typedef float f4v __attribute__((ext_vector_type(4)));

// ws layout (float units):
//   XV  : Vp*3*Hp floats    x-side projections per vocab id (incl. input biases), fp32
//   Whi : 3*Hp*Hp ushorts   bf16 hi weights, row = ((j>>4)*3+g)*16 + (j&15), k-contiguous
//   Wlo : 3*Hp*Hp ushorts   bf16 lo residual weights, same layout
//   hhi : 2*Bp*Hp ushorts   bf16 hi of h, ping-pong
//   hlo : 2*Bp*Hp ushorts   bf16 lo of h, ping-pong
//   ys  : Sp*Bp*Hp floats   all hidden states fp32, [s][b][h]
#define WS_XV   0
#define WS_WHI  (WS_XV + Vp*3*Hp)
#define WS_WLO  (WS_WHI + (3*Hp*Hp)/2)
#define WS_HHI  (WS_WLO + (3*Hp*Hp)/2)
#define WS_HLO  (WS_HHI + (2*Bp*Hp)/2)
#define WS_YS   (WS_HLO + (2*Bp*Hp)/2)
#define WS_FLOATS (WS_YS + (size_t)Sp*Bp*Hp)

__device__ __forceinline__ unsigned short f2bf(float x) {
  union { float f; unsigned u; } v; v.f = x;
  unsigned r = v.u + 0x7fffu + ((v.u >> 16) & 1u);   // RNE
  return (unsigned short)(r >> 16);
}
__device__ __forceinline__ float bf2f(unsigned short h) {
  union { unsigned u; float f; } v; v.u = ((unsigned)h) << 16;
  return v.f;
}

// ---------------------------------------------------------------- XV precompute
__global__ __launch_bounds__(256) void xv_kernel(
    const float* __restrict__ emb,
    const float* __restrict__ Wir, const float* __restrict__ bir,
    const float* __restrict__ Wiz, const float* __restrict__ biz,
    const float* __restrict__ Win, const float* __restrict__ bin_,
    float* __restrict__ XV) {
  int n = blockIdx.x * 256 + threadIdx.x;   // 0..3071
  int v = blockIdx.y;                        // 0..127
  int g = n >> 10;
  int j = n & (Hp - 1);
  const float* W = (g == 0) ? Wir : ((g == 1) ? Wiz : Win);
  const float* bias = (g == 0) ? bir : ((g == 1) ? biz : bin_);
  float acc = bias[j];
  const float* ev = emb + (size_t)v * Ep;
  for (int e = 0; e < Ep; ++e) acc += ev[e] * W[(size_t)e * Hp + j];
  XV[(size_t)v * (3 * Hp) + n] = acc;
}

// ---------------------------------------------------------------- weight pack (bf16 hi/lo split)
__global__ void wpack_kernel(const float* __restrict__ Whr,
                             const float* __restrict__ Whz,
                             const float* __restrict__ Whn,
                             unsigned short* __restrict__ Whi,
                             unsigned short* __restrict__ Wlo) {
  __shared__ float tile[32][33];
  int g = blockIdx.z;
  const float* src = (g == 0) ? Whr : ((g == 1) ? Whz : Whn);
  int kb = blockIdx.x * 32;
  int jb32 = blockIdx.y * 32;
  int tx = threadIdx.x, ty = threadIdx.y;  // 32 x 8
  #pragma unroll
  for (int i = 0; i < 4; ++i)
    tile[ty + 8 * i][tx] = src[(size_t)(kb + ty + 8 * i) * Hp + (jb32 + tx)];
  __syncthreads();
  #pragma unroll
  for (int i = 0; i < 4; ++i) {
    int jl = ty + 8 * i;
    int j = jb32 + jl;
    int dstRow = ((j >> 4) * 3 + g) * 16 + (j & 15);
    float w = tile[tx][jl];
    unsigned short hi = f2bf(w);
    Whi[(size_t)dstRow * Hp + kb + tx] = hi;
    Wlo[(size_t)dstRow * Hp + kb + tx] = f2bf(w - bf2f(hi));
  }
}

// ---------------------------------------------------------------- h0 -> bf16 hi/lo
__global__ void h0_kernel(const float* __restrict__ carry,
                          unsigned short* __restrict__ hhi,
                          unsigned short* __restrict__ hlo) {
  int i = blockIdx.x * 256 + threadIdx.x;
  float h = carry[i];
  unsigned short hi = f2bf(h);
  hhi[i] = hi;
  hlo[i] = f2bf(h - bf2f(hi));
}

// ---------------------------------------------------------------- persistent MFMA GRU scan
// 256 blocks x 256 threads (4 waves). block = (mb = blockIdx&3: 16 batches) x
// (jb = blockIdx>>2: 16 cols x 3 gates). Wave w owns K-quarter [256w,256w+256).
// Weights (bf16 hi+lo B-frags) live in REGISTERS for all 512 steps (192 VGPR).
// Per step: 16 A-frag loads, 72 MFMA, LDS cross-wave K-reduce, epilogue
// (1 elem/thread), grid.sync.
__global__ __launch_bounds__(256, 1) void gru_scan(
    const float* __restrict__ carry,
    float* __restrict__ ys,
    const unsigned short* __restrict__ Whi,
    const unsigned short* __restrict__ Wlo,
    const float* __restrict__ XV,
    const int* __restrict__ toks,
    const float* __restrict__ bhn,
    unsigned short* __restrict__ hhi,
    unsigned short* __restrict__ hlo) {
  __shared__ float part[3 * 4 * 64 * 4];   // [g][wave][lane][reg] = 12 KB
  __shared__ int tkl[16 * Sp];             // this block's 16 rows of tokens, 32 KB

  cg::grid_group grid = cg::this_grid();
  const int tid = threadIdx.x;
  const int wv = tid >> 6, lane = tid & 63;
  const int mb = blockIdx.x & 3, jb = blockIdx.x >> 2;
  const int col = lane & 15, kq = lane >> 4;

  // stage tokens (coalesced)
  for (int i = tid; i < 16 * Sp; i += 256)
    tkl[i] = toks[(size_t)(mb * 16 + (i >> 9)) * Sp + (i & (Sp - 1))];

  // preload B fragments — loop-invariant, stays in registers (48 s8v = 192 VGPR)
  s8v bh[3][8], bl[3][8];
  const int kbase = wv * 256 + kq * 8;
  #pragma unroll
  for (int g = 0; g < 3; ++g) {
    const size_t rowoff = ((size_t)(jb * 3 + g) * 16 + col) * Hp + kbase;
    #pragma unroll
    for (int c = 0; c < 8; ++c) {
      bh[g][c] = *(const s8v*)(Whi + rowoff + c * 32);
      bl[g][c] = *(const s8v*)(Wlo + rowoff + c * 32);
    }
  }

  // epilogue mapping: thread -> one output element (16x16 tile)
  const int erow = tid >> 4, ecol = tid & 15;
  const int eb = mb * 16 + erow;
  const int ej = jb * 16 + ecol;
  const int elane = (erow >> 2) * 16 + ecol;
  const int er = erow & 3;
  const float bhnv = bhn[ej];

  const size_t aBase = (size_t)(mb * 16 + col) * Hp + kbase;

  __syncthreads();

  for (int t = 0; t < Sp; ++t) {
    const unsigned short* hhiR = hhi + (size_t)(t & 1) * (Bp * Hp);
    const unsigned short* hloR = hlo + (size_t)(t & 1) * (Bp * Hp);
    unsigned short* hhiW = hhi + (size_t)((t + 1) & 1) * (Bp * Hp);
    unsigned short* hloW = hlo + (size_t)((t + 1) & 1) * (Bp * Hp);

    // A fragments: h hi/lo for this wave's K-quarter
    s8v ah[8], al[8];
    #pragma unroll
    for (int c = 0; c < 8; ++c) {
      ah[c] = *(const s8v*)(hhiR + aBase + (size_t)c * 32);
      al[c] = *(const s8v*)(hloR + aBase + (size_t)c * 32);
    }

    f4v ar = {0.f, 0.f, 0.f, 0.f}, az = {0.f, 0.f, 0.f, 0.f}, an = {0.f, 0.f, 0.f, 0.f};
    #pragma unroll
    for (int c = 0; c < 8; ++c) {
      ar = __builtin_amdgcn_mfma_f32_16x16x32_bf16(ah[c], bh[0][c], ar, 0, 0, 0);
      az = __builtin_amdgcn_mfma_f32_16x16x32_bf16(ah[c], bh[1][c], az, 0, 0, 0);
      an = __builtin_amdgcn_mfma_f32_16x16x32_bf16(ah[c], bh[2][c], an, 0, 0, 0);
      ar = __builtin_amdgcn_mfma_f32_16x16x32_bf16(al[c], bh[0][c], ar, 0, 0, 0);
      az = __builtin_amdgcn_mfma_f32_16x16x32_bf16(al[c], bh[1][c], az, 0, 0, 0);
      an = __builtin_amdgcn_mfma_f32_16x16x32_bf16(al[c], bh[2][c], an, 0, 0, 0);
      ar = __builtin_amdgcn_mfma_f32_16x16x32_bf16(ah[c], bl[0][c], ar, 0, 0, 0);
      az = __builtin_amdgcn_mfma_f32_16x16x32_bf16(ah[c], bl[1][c], az, 0, 0, 0);
      an = __builtin_amdgcn_mfma_f32_16x16x32_bf16(ah[c], bl[2][c], an, 0, 0, 0);
    }

    // cross-wave K reduction via LDS
    *(f4v*)&part[((0 * 4 + wv) * 64 + lane) * 4] = ar;
    *(f4v*)&part[((1 * 4 + wv) * 64 + lane) * 4] = az;
    *(f4v*)&part[((2 * 4 + wv) * 64 + lane) * 4] = an;
    __syncthreads();

    // epilogue: one element per thread
    float sr = 0.f, sz = 0.f, sn = 0.f;
    #pragma unroll
    for (int w = 0; w < 4; ++w) {
      sr += part[((0 * 4 + w) * 64 + elane) * 4 + er];
      sz += part[((1 * 4 + w) * 64 + elane) * 4 + er];
      sn += part[((2 * 4 + w) * 64 + elane) * 4 + er];
    }
    int tok = tkl[erow * Sp + t];
    const float* xvp = XV + (size_t)tok * (3 * Hp) + ej;
    float xr = xvp[0];
    float xz = xvp[Hp];
    float xn = xvp[2 * Hp];
    const float* hpf = (t == 0) ? carry : (ys + (size_t)(t - 1) * (Bp * Hp));
    float hold = hpf[(size_t)eb * Hp + ej];

    float rg = 1.f / (1.f + expf(-(sr + xr)));
    float zg = 1.f / (1.f + expf(-(sz + xz)));
    float ng = tanhf(xn + rg * (sn + bhnv));
    float hnew = (1.f - zg) * ng + zg * hold;

    ys[(size_t)t * (Bp * Hp) + (size_t)eb * Hp + ej] = hnew;
    unsigned short hi16 = f2bf(hnew);
    hhiW[(size_t)eb * Hp + ej] = hi16;
    hloW[(size_t)eb * Hp + ej] = f2bf(hnew - bf2f(hi16));

    grid.sync();
  }
}

// ---------------------------------------------------------------- fused output denses
__global__ __launch_bounds__(256) void dense_kernel(
    const float* __restrict__ ys,   // [S][B][H]
    const float* __restrict__ Wh, const float* __restrict__ bh,
    const float* __restrict__ Wo, const float* __restrict__ bo,
    float* __restrict__ out) {      // logits at out + B*H
  __shared__ float hs[16][1032];
  __shared__ float hid[16][1032];
  int tid = threadIdx.x;
  int r0 = blockIdx.x * 16;
  int bq = r0 / Sp;        // constant within tile (S % 16 == 0)
  int s0 = r0 % Sp;

  for (int i = tid; i < 16 * 256; i += 256) {
    int m = i >> 8;
    int f = i & 255;
    float4 v = ((const float4*)(ys + (size_t)(s0 + m) * (Bp * Hp) + (size_t)bq * Hp))[f];
    ((float4*)&hs[m][0])[f] = v;
  }
  __syncthreads();

  float4 acc[16];
  float4 bh4 = ((const float4*)bh)[tid];
  #pragma unroll
  for (int m = 0; m < 16; ++m) acc[m] = bh4;
  for (int k = 0; k < Hp; ++k) {
    float4 w = ((const float4*)(Wh + (size_t)k * Hp))[tid];
    #pragma unroll
    for (int m = 0; m < 16; ++m) {
      float hv = hs[m][k];
      acc[m].x += hv * w.x;
      acc[m].y += hv * w.y;
      acc[m].z += hv * w.z;
      acc[m].w += hv * w.w;
    }
  }
  #pragma unroll
  for (int m = 0; m < 16; ++m) ((float4*)&hid[m][0])[tid] = acc[m];
  __syncthreads();

  int o = tid & (Op - 1);
  int half = tid >> 7;
  float lacc[8];
  float bov = bo[o];
  #pragma unroll
  for (int mm = 0; mm < 8; ++mm) lacc[mm] = bov;
  for (int k = 0; k < Hp; ++k) {
    float wo = Wo[(size_t)k * Op + o];
    #pragma unroll
    for (int mm = 0; mm < 8; ++mm) lacc[mm] += hid[half * 8 + mm][k] * wo;
  }
  float* lo = out + (size_t)Bp * Hp;
  #pragma unroll
  for (int mm = 0; mm < 8; ++mm) {
    int r = r0 + half * 8 + mm;
    lo[(size_t)r * Op + o] = lacc[mm];
  }
}

// ---------------------------------------------------------------- carry out
__global__ void carry_kernel(const float* __restrict__ ys, float* __restrict__ out) {
  int i = blockIdx.x * 256 + threadIdx.x;
  out[i] = ys[(size_t)(Sp - 1) * (Bp * Hp) + i];
}

extern "C" void kernel_launch(void* const* d_in, const int* in_sizes, int n_in,
                              void* d_out, int out_size, void* d_ws, size_t ws_size,
                              hipStream_t stream) {
  const int*   toks = (const int*)  d_in[0];
  const float* carry= (const float*)d_in[1];
  const float* emb  = (const float*)d_in[2];
  const float* Wir  = (const float*)d_in[3];
  const float* bir  = (const float*)d_in[4];
  const float* Whr  = (const float*)d_in[5];
  const float* Wiz  = (const float*)d_in[6];
  const float* biz  = (const float*)d_in[7];
  const float* Whz  = (const float*)d_in[8];
  const float* Win  = (const float*)d_in[9];
  const float* bin_ = (const float*)d_in[10];
  const float* Whn  = (const float*)d_in[11];
  const float* bhn  = (const float*)d_in[12];
  const float* Wh   = (const float*)d_in[13];
  const float* bh   = (const float*)d_in[14];
  const float* Wo   = (const float*)d_in[15];
  const float* bo   = (const float*)d_in[16];
  float* out = (float*)d_out;

  if (ws_size < WS_FLOATS * sizeof(float)) return;

  float* ws = (float*)d_ws;
  float* XV = ws + WS_XV;
  unsigned short* WhiP = (unsigned short*)(ws + WS_WHI);
  unsigned short* WloP = (unsigned short*)(ws + WS_WLO);
  unsigned short* hhi  = (unsigned short*)(ws + WS_HHI);
  unsigned short* hlo  = (unsigned short*)(ws + WS_HLO);
  float* ys = ws + WS_YS;

  // preps
  xv_kernel<<<dim3(12, Vp), 256, 0, stream>>>(emb, Wir, bir, Wiz, biz, Win, bin_, XV);
  wpack_kernel<<<dim3(Hp / 32, Hp / 32, 3), dim3(32, 8), 0, stream>>>(Whr, Whz, Whn, WhiP, WloP);
  h0_kernel<<<(Bp * Hp) / 256, 256, 0, stream>>>(carry, hhi, hlo);

  // persistent cooperative MFMA scan
  {
    void* args[] = {(void*)&carry, (void*)&ys, (void*)&WhiP, (void*)&WloP,
                    (void*)&XV, (void*)&toks, (void*)&bhn,
                    (void*)&hhi, (void*)&hlo};
    hipLaunchCooperativeKernel((const void*)gru_scan, dim3(256), dim3(256),
                               args, 0, stream);
  }

  // outputs
  carry_kernel<<<(Bp * Hp) / 256, 256, 0, stream>>>(ys, out);
  dense_kernel<<<(Bp * Sp) / 16, 256, 0, stream>>>(ys, Wh, bh, Wo, bo, out);
}

// Round 5
// 13490.024 us; speedup vs baseline: 3.8819x; 1.4225x over previous
//
#include <hip/hip_runtime.h>
#include <hip/hip_cooperative_groups.h>
#include <math.h>

namespace cg = cooperative_groups;

#define Bp 64
#define Sp 512
#define Ep 128
#define Hp 1024
#define Vp 128
#define Op 128

typedef short s8v __attribute__((ext_vector_type(8)));
typedef float f4v __attribute__((ext_vector_type(4)));

// ws layout (float units):
//   XV  : Vp*3*Hp floats    x-side projections per vocab id (incl. input biases), fp32
//   Whi : 3*Hp*Hp ushorts   bf16 hi weights, row = ((j>>4)*3+g)*16 + (j&15), k-contiguous
//   Wlo : 3*Hp*Hp ushorts   bf16 lo residual weights, same layout
//   hhi : 2*Bp*Hp ushorts   bf16 hi of h, ping-pong
//   hlo : 2*Bp*Hp ushorts   bf16 lo of h, ping-pong
//   ys  : Sp*Bp*Hp floats   all hidden states fp32, [s][b][h]
//   bar : 4*256 uints       per-group barrier counters (1 KB apart)
#define WS_XV   0
#define WS_WHI  (WS_XV + Vp*3*Hp)
#define WS_WLO  (WS_WHI + (3*Hp*Hp)/2)
#define WS_HHI  (WS_WLO + (3*Hp*Hp)/2)
#define WS_HLO  (WS_HHI + (2*Bp*Hp)/2)
#define WS_YS   (WS_HLO + (2*Bp*Hp)/2)
#define WS_BAR  (WS_YS + (size_t)Sp*Bp*Hp)
#define WS_FLOATS (WS_BAR + 4*256)

__device__ __forceinline__ unsigned short f2bf(float x) {
  union { float f; unsigned u; } v; v.f = x;
  unsigned r = v.u + 0x7fffu + ((v.u >> 16) & 1u);   // RNE
  return (unsigned short)(r >> 16);
}
__device__ __forceinline__ float bf2f(unsigned short h) {
  union { unsigned u; float f; } v; v.u = ((unsigned)h) << 16;
  return v.f;
}

// ---------------------------------------------------------------- XV precompute
__global__ __launch_bounds__(256) void xv_kernel(
    const float* __restrict__ emb,
    const float* __restrict__ Wir, const float* __restrict__ bir,
    const float* __restrict__ Wiz, const float* __restrict__ biz,
    const float* __restrict__ Win, const float* __restrict__ bin_,
    float* __restrict__ XV) {
  int n = blockIdx.x * 256 + threadIdx.x;   // 0..3071
  int v = blockIdx.y;                        // 0..127
  int g = n >> 10;
  int j = n & (Hp - 1);
  const float* W = (g == 0) ? Wir : ((g == 1) ? Wiz : Win);
  const float* bias = (g == 0) ? bir : ((g == 1) ? biz : bin_);
  float acc = bias[j];
  const float* ev = emb + (size_t)v * Ep;
  for (int e = 0; e < Ep; ++e) acc += ev[e] * W[(size_t)e * Hp + j];
  XV[(size_t)v * (3 * Hp) + n] = acc;
}

// ---------------------------------------------------------------- weight pack (bf16 hi/lo split)
__global__ void wpack_kernel(const float* __restrict__ Whr,
                             const float* __restrict__ Whz,
                             const float* __restrict__ Whn,
                             unsigned short* __restrict__ Whi,
                             unsigned short* __restrict__ Wlo) {
  __shared__ float tile[32][33];
  int g = blockIdx.z;
  const float* src = (g == 0) ? Whr : ((g == 1) ? Whz : Whn);
  int kb = blockIdx.x * 32;
  int jb32 = blockIdx.y * 32;
  int tx = threadIdx.x, ty = threadIdx.y;  // 32 x 8
  #pragma unroll
  for (int i = 0; i < 4; ++i)
    tile[ty + 8 * i][tx] = src[(size_t)(kb + ty + 8 * i) * Hp + (jb32 + tx)];
  __syncthreads();
  #pragma unroll
  for (int i = 0; i < 4; ++i) {
    int jl = ty + 8 * i;
    int j = jb32 + jl;
    int dstRow = ((j >> 4) * 3 + g) * 16 + (j & 15);
    float w = tile[tx][jl];
    unsigned short hi = f2bf(w);
    Whi[(size_t)dstRow * Hp + kb + tx] = hi;
    Wlo[(size_t)dstRow * Hp + kb + tx] = f2bf(w - bf2f(hi));
  }
}

// ---------------------------------------------------------------- h0 -> bf16 hi/lo ; zero barriers
__global__ void h0_kernel(const float* __restrict__ carry,
                          unsigned short* __restrict__ hhi,
                          unsigned short* __restrict__ hlo,
                          unsigned* __restrict__ bar) {
  int i = blockIdx.x * 256 + threadIdx.x;
  float h = carry[i];
  unsigned short hi = f2bf(h);
  hhi[i] = hi;
  hlo[i] = f2bf(h - bf2f(hi));
  if (i < 4 * 256) bar[i] = 0u;
}

// ---------------------------------------------------------------- persistent MFMA GRU scan
// 256 blocks x 256 threads (4 waves). block = (mb = blockIdx&3: 16 batches) x
// (jb = blockIdx>>2: 16 cols x 3 gates). Wave w owns K-quarter.
// 4 INDEPENDENT groups (one per mb): batches are independent recurrences, so
// each group of 64 blocks syncs only among itself via a monotonic atomic
// counter barrier (device scope). hold/token/XV are register-carried or
// prefetched — no dependent global loads in the epilogue except A-frags.
__global__ __launch_bounds__(256, 1) void gru_scan(
    const float* __restrict__ carry,
    float* __restrict__ ys,
    const unsigned short* __restrict__ Whi,
    const unsigned short* __restrict__ Wlo,
    const float* __restrict__ XV,
    const int* __restrict__ toks,
    const float* __restrict__ bhn,
    unsigned short* __restrict__ hhi,
    unsigned short* __restrict__ hlo,
    unsigned* __restrict__ bar) {
  __shared__ float part[3 * 4 * 64 * 4];   // [g][wave][lane][reg] = 12 KB

  const int tid = threadIdx.x;
  const int wv = tid >> 6, lane = tid & 63;
  const int mb = blockIdx.x & 3, jb = blockIdx.x >> 2;
  const int col = lane & 15, kq = lane >> 4;

  unsigned* ctr = bar + mb * 256;          // group counter, 1 KB apart

  // B-frag base pointers (wave's K-quarter)
  const int kbase = wv * 256 + kq * 8;
  const unsigned short* bhp[3];
  const unsigned short* blp[3];
  #pragma unroll
  for (int g = 0; g < 3; ++g) {
    const size_t rowoff = ((size_t)(jb * 3 + g) * 16 + col) * Hp + kbase;
    bhp[g] = Whi + rowoff;
    blp[g] = Wlo + rowoff;
  }

  // epilogue mapping: thread -> one output element (16x16 tile)
  const int erow = tid >> 4, ecol = tid & 15;
  const int eb = mb * 16 + erow;
  const int ej = jb * 16 + ecol;
  const int elane = (erow >> 2) * 16 + ecol;
  const int er = erow & 3;
  const float bhnv = bhn[ej];

  const size_t aBase = (size_t)(mb * 16 + col) * Hp + kbase;
  const size_t eOff = (size_t)eb * Hp + ej;

  // register-carried state
  float holdR = carry[eOff];
  // t=0 epilogue operands
  int tok0 = toks[eb * Sp + 0];
  const float* xvp0 = XV + (size_t)tok0 * (3 * Hp) + ej;
  float xr = xvp0[0], xz = xvp0[Hp], xn = xvp0[2 * Hp];

  for (int t = 0; t < Sp; ++t) {
    const unsigned short* hhiR = hhi + (size_t)(t & 1) * (Bp * Hp);
    const unsigned short* hloR = hlo + (size_t)(t & 1) * (Bp * Hp);
    unsigned short* hhiW = hhi + (size_t)((t + 1) & 1) * (Bp * Hp);
    unsigned short* hloW = hlo + (size_t)((t + 1) & 1) * (Bp * Hp);

    // A fragments: h hi/lo for this wave's K-quarter (the only barrier-dependent loads)
    s8v ah[8], al[8];
    #pragma unroll
    for (int c = 0; c < 8; ++c) {
      ah[c] = *(const s8v*)(hhiR + aBase + (size_t)c * 32);
      al[c] = *(const s8v*)(hloR + aBase + (size_t)c * 32);
    }

    // prefetch next step's token + XV gate values (independent of h)
    float xrN, xzN, xnN;
    {
      int tN = (t + 1 < Sp) ? (t + 1) : t;
      int tokN = toks[eb * Sp + tN];
      const float* xvpN = XV + (size_t)tokN * (3 * Hp) + ej;
      xrN = xvpN[0];
      xzN = xvpN[Hp];
      xnN = xvpN[2 * Hp];
    }

    f4v ar = {0.f, 0.f, 0.f, 0.f}, az = {0.f, 0.f, 0.f, 0.f}, an = {0.f, 0.f, 0.f, 0.f};
    #pragma unroll
    for (int c = 0; c < 8; ++c) {
      s8v b0 = *(const s8v*)(bhp[0] + c * 32);
      s8v b1 = *(const s8v*)(bhp[1] + c * 32);
      s8v b2 = *(const s8v*)(bhp[2] + c * 32);
      s8v l0 = *(const s8v*)(blp[0] + c * 32);
      s8v l1 = *(const s8v*)(blp[1] + c * 32);
      s8v l2 = *(const s8v*)(blp[2] + c * 32);
      ar = __builtin_amdgcn_mfma_f32_16x16x32_bf16(ah[c], b0, ar, 0, 0, 0);
      az = __builtin_amdgcn_mfma_f32_16x16x32_bf16(ah[c], b1, az, 0, 0, 0);
      an = __builtin_amdgcn_mfma_f32_16x16x32_bf16(ah[c], b2, an, 0, 0, 0);
      ar = __builtin_amdgcn_mfma_f32_16x16x32_bf16(al[c], b0, ar, 0, 0, 0);
      az = __builtin_amdgcn_mfma_f32_16x16x32_bf16(al[c], b1, az, 0, 0, 0);
      an = __builtin_amdgcn_mfma_f32_16x16x32_bf16(al[c], b2, an, 0, 0, 0);
      ar = __builtin_amdgcn_mfma_f32_16x16x32_bf16(ah[c], l0, ar, 0, 0, 0);
      az = __builtin_amdgcn_mfma_f32_16x16x32_bf16(ah[c], l1, az, 0, 0, 0);
      an = __builtin_amdgcn_mfma_f32_16x16x32_bf16(ah[c], l2, an, 0, 0, 0);
    }

    // cross-wave K reduction via LDS
    *(f4v*)&part[((0 * 4 + wv) * 64 + lane) * 4] = ar;
    *(f4v*)&part[((1 * 4 + wv) * 64 + lane) * 4] = az;
    *(f4v*)&part[((2 * 4 + wv) * 64 + lane) * 4] = an;
    __syncthreads();

    float sr = 0.f, sz = 0.f, sn = 0.f;
    #pragma unroll
    for (int w = 0; w < 4; ++w) {
      sr += part[((0 * 4 + w) * 64 + elane) * 4 + er];
      sz += part[((1 * 4 + w) * 64 + elane) * 4 + er];
      sn += part[((2 * 4 + w) * 64 + elane) * 4 + er];
    }

    float rg = 1.f / (1.f + expf(-(sr + xr)));
    float zg = 1.f / (1.f + expf(-(sz + xz)));
    float ng = tanhf(xn + rg * (sn + bhnv));
    float hnew = (1.f - zg) * ng + zg * holdR;

    __builtin_nontemporal_store(hnew, ys + (size_t)t * (Bp * Hp) + eOff);
    unsigned short hi16 = f2bf(hnew);
    __builtin_nontemporal_store(hi16, hhiW + eOff);
    __builtin_nontemporal_store(f2bf(hnew - bf2f(hi16)), hloW + eOff);

    holdR = hnew;
    xr = xrN; xz = xzN; xn = xnN;

    // ---- group barrier (64 blocks, monotonic counter) ----
    __syncthreads();                      // drains vmcnt before s_barrier
    if (tid == 0) {
      __threadfence();                    // release: writeback so group sees h
      __hip_atomic_fetch_add(ctr, 1u, __ATOMIC_RELEASE, __HIP_MEMORY_SCOPE_AGENT);
      unsigned target = 64u * (unsigned)(t + 1);
      while (__hip_atomic_load(ctr, __ATOMIC_ACQUIRE, __HIP_MEMORY_SCOPE_AGENT) < target)
        __builtin_amdgcn_s_sleep(1);
      __threadfence();                    // acquire: invalidate stale caches
    }
    __syncthreads();
  }
}

// ---------------------------------------------------------------- fused output denses
__global__ __launch_bounds__(256) void dense_kernel(
    const float* __restrict__ ys,   // [S][B][H]
    const float* __restrict__ Wh, const float* __restrict__ bh,
    const float* __restrict__ Wo, const float* __restrict__ bo,
    float* __restrict__ out) {      // logits at out + B*H
  __shared__ float hs[16][1032];
  __shared__ float hid[16][1032];
  int tid = threadIdx.x;
  int r0 = blockIdx.x * 16;
  int bq = r0 / Sp;        // constant within tile (S % 16 == 0)
  int s0 = r0 % Sp;

  for (int i = tid; i < 16 * 256; i += 256) {
    int m = i >> 8;
    int f = i & 255;
    float4 v = ((const float4*)(ys + (size_t)(s0 + m) * (Bp * Hp) + (size_t)bq * Hp))[f];
    ((float4*)&hs[m][0])[f] = v;
  }
  __syncthreads();

  float4 acc[16];
  float4 bh4 = ((const float4*)bh)[tid];
  #pragma unroll
  for (int m = 0; m < 16; ++m) acc[m] = bh4;
  for (int k = 0; k < Hp; ++k) {
    float4 w = ((const float4*)(Wh + (size_t)k * Hp))[tid];
    #pragma unroll
    for (int m = 0; m < 16; ++m) {
      float hv = hs[m][k];
      acc[m].x += hv * w.x;
      acc[m].y += hv * w.y;
      acc[m].z += hv * w.z;
      acc[m].w += hv * w.w;
    }
  }
  #pragma unroll
  for (int m = 0; m < 16; ++m) ((float4*)&hid[m][0])[tid] = acc[m];
  __syncthreads();

  int o = tid & (Op - 1);
  int half = tid >> 7;
  float lacc[8];
  float bov = bo[o];
  #pragma unroll
  for (int mm = 0; mm < 8; ++mm) lacc[mm] = bov;
  for (int k = 0; k < Hp; ++k) {
    float wo = Wo[(size_t)k * Op + o];
    #pragma unroll
    for (int mm = 0; mm < 8; ++mm) lacc[mm] += hid[half * 8 + mm][k] * wo;
  }
  float* lo = out + (size_t)Bp * Hp;
  #pragma unroll
  for (int mm = 0; mm < 8; ++mm) {
    int r = r0 + half * 8 + mm;
    lo[(size_t)r * Op + o] = lacc[mm];
  }
}

// ---------------------------------------------------------------- carry out
__global__ void carry_kernel(const float* __restrict__ ys, float* __restrict__ out) {
  int i = blockIdx.x * 256 + threadIdx.x;
  out[i] = ys[(size_t)(Sp - 1) * (Bp * Hp) + i];
}

extern "C" void kernel_launch(void* const* d_in, const int* in_sizes, int n_in,
                              void* d_out, int out_size, void* d_ws, size_t ws_size,
                              hipStream_t stream) {
  const int*   toks = (const int*)  d_in[0];
  const float* carry= (const float*)d_in[1];
  const float* emb  = (const float*)d_in[2];
  const float* Wir  = (const float*)d_in[3];
  const float* bir  = (const float*)d_in[4];
  const float* Whr  = (const float*)d_in[5];
  const float* Wiz  = (const float*)d_in[6];
  const float* biz  = (const float*)d_in[7];
  const float* Whz  = (const float*)d_in[8];
  const float* Win  = (const float*)d_in[9];
  const float* bin_ = (const float*)d_in[10];
  const float* Whn  = (const float*)d_in[11];
  const float* bhn  = (const float*)d_in[12];
  const float* Wh   = (const float*)d_in[13];
  const float* bh   = (const float*)d_in[14];
  const float* Wo   = (const float*)d_in[15];
  const float* bo   = (const float*)d_in[16];
  float* out = (float*)d_out;

  if (ws_size < WS_FLOATS * sizeof(float)) return;

  float* ws = (float*)d_ws;
  float* XV = ws + WS_XV;
  unsigned short* WhiP = (unsigned short*)(ws + WS_WHI);
  unsigned short* WloP = (unsigned short*)(ws + WS_WLO);
  unsigned short* hhi  = (unsigned short*)(ws + WS_HHI);
  unsigned short* hlo  = (unsigned short*)(ws + WS_HLO);
  float* ys = ws + WS_YS;
  unsigned* bar = (unsigned*)(ws + WS_BAR);

  // preps
  xv_kernel<<<dim3(12, Vp), 256, 0, stream>>>(emb, Wir, bir, Wiz, biz, Win, bin_, XV);
  wpack_kernel<<<dim3(Hp / 32, Hp / 32, 3), dim3(32, 8), 0, stream>>>(Whr, Whz, Whn, WhiP, WloP);
  h0_kernel<<<(Bp * Hp) / 256, 256, 0, stream>>>(carry, hhi, hlo, bar);

  // persistent cooperative MFMA scan (co-residency guarantee; own group barriers)
  {
    void* args[] = {(void*)&carry, (void*)&ys, (void*)&WhiP, (void*)&WloP,
                    (void*)&XV, (void*)&toks, (void*)&bhn,
                    (void*)&hhi, (void*)&hlo, (void*)&bar};
    hipLaunchCooperativeKernel((const void*)gru_scan, dim3(256), dim3(256),
                               args, 0, stream);
  }

  // outputs
  carry_kernel<<<(Bp * Hp) / 256, 256, 0, stream>>>(ys, out);
  dense_kernel<<<(Bp * Sp) / 16, 256, 0, stream>>>(ys, Wh, bh, Wo, bo, out);
}

// Round 6
// 5477.617 us; speedup vs baseline: 9.5602x; 2.4628x over previous
//
#include <hip/hip_runtime.h>
#include <hip/hip_cooperative_groups.h>
#include <math.h>

namespace cg = cooperative_groups;

#define Bp 64
#define Sp 512
#define Ep 128
#define Hp 1024
#define Vp 128
#define Op 128

typedef short s8v __attribute__((ext_vector_type(8)));
typedef float f4v __attribute__((ext_vector_type(4)));

// ws layout (float units):
//   XV  : Vp*3*Hp floats    x-side projections per vocab id (incl. input biases), fp32
//   Whi : 3*Hp*Hp ushorts   bf16 hi weights, row = ((j>>4)*3+g)*16 + (j&15), k-contiguous
//   Wlo : 3*Hp*Hp ushorts   bf16 lo residual weights, same layout
//   hhi : 2*Bp*Hp ushorts   bf16 hi of h, ping-pong (agent-coherent via sc1 atomics)
//   hlo : 2*Bp*Hp ushorts   bf16 lo of h, ping-pong (agent-coherent via sc1 atomics)
//   ys  : Sp*Bp*Hp floats   all hidden states fp32, [s][b][h]
//   bar : 4*256 uints       per-group barrier counters (1 KB apart)
#define WS_XV   0
#define WS_WHI  (WS_XV + Vp*3*Hp)
#define WS_WLO  (WS_WHI + (3*Hp*Hp)/2)
#define WS_HHI  (WS_WLO + (3*Hp*Hp)/2)
#define WS_HLO  (WS_HHI + (2*Bp*Hp)/2)
#define WS_YS   (WS_HLO + (2*Bp*Hp)/2)
#define WS_BAR  (WS_YS + (size_t)Sp*Bp*Hp)
#define WS_FLOATS (WS_BAR + 4*256)

__device__ __forceinline__ unsigned short f2bf(float x) {
  union { float f; unsigned u; } v; v.f = x;
  unsigned r = v.u + 0x7fffu + ((v.u >> 16) & 1u);   // RNE
  return (unsigned short)(r >> 16);
}
__device__ __forceinline__ float bf2f(unsigned short h) {
  union { unsigned u; float f; } v; v.u = ((unsigned)h) << 16;
  return v.f;
}

// agent-coherent 16B load as two 8B relaxed atomics (global_load sc1 — reads
// the coherence point; immune to stale per-XCD L2, placement-independent)
__device__ __forceinline__ s8v ald16(const unsigned short* p) {
  union { unsigned long long q[2]; s8v v; } u;
  const unsigned long long* qp = (const unsigned long long*)p;
  u.q[0] = __hip_atomic_load(qp,     __ATOMIC_RELAXED, __HIP_MEMORY_SCOPE_AGENT);
  u.q[1] = __hip_atomic_load(qp + 1, __ATOMIC_RELAXED, __HIP_MEMORY_SCOPE_AGENT);
  return u.v;
}
__device__ __forceinline__ void ast8(unsigned short* p, unsigned long long v) {
  __hip_atomic_store((unsigned long long*)p, v, __ATOMIC_RELAXED, __HIP_MEMORY_SCOPE_AGENT);
}

// ---------------------------------------------------------------- XV precompute
__global__ __launch_bounds__(256) void xv_kernel(
    const float* __restrict__ emb,
    const float* __restrict__ Wir, const float* __restrict__ bir,
    const float* __restrict__ Wiz, const float* __restrict__ biz,
    const float* __restrict__ Win, const float* __restrict__ bin_,
    float* __restrict__ XV) {
  int n = blockIdx.x * 256 + threadIdx.x;   // 0..3071
  int v = blockIdx.y;                        // 0..127
  int g = n >> 10;
  int j = n & (Hp - 1);
  const float* W = (g == 0) ? Wir : ((g == 1) ? Wiz : Win);
  const float* bias = (g == 0) ? bir : ((g == 1) ? biz : bin_);
  float acc = bias[j];
  const float* ev = emb + (size_t)v * Ep;
  for (int e = 0; e < Ep; ++e) acc += ev[e] * W[(size_t)e * Hp + j];
  XV[(size_t)v * (3 * Hp) + n] = acc;
}

// ---------------------------------------------------------------- weight pack (bf16 hi/lo split)
__global__ void wpack_kernel(const float* __restrict__ Whr,
                             const float* __restrict__ Whz,
                             const float* __restrict__ Whn,
                             unsigned short* __restrict__ Whi,
                             unsigned short* __restrict__ Wlo) {
  __shared__ float tile[32][33];
  int g = blockIdx.z;
  const float* src = (g == 0) ? Whr : ((g == 1) ? Whz : Whn);
  int kb = blockIdx.x * 32;
  int jb32 = blockIdx.y * 32;
  int tx = threadIdx.x, ty = threadIdx.y;  // 32 x 8
  #pragma unroll
  for (int i = 0; i < 4; ++i)
    tile[ty + 8 * i][tx] = src[(size_t)(kb + ty + 8 * i) * Hp + (jb32 + tx)];
  __syncthreads();
  #pragma unroll
  for (int i = 0; i < 4; ++i) {
    int jl = ty + 8 * i;
    int j = jb32 + jl;
    int dstRow = ((j >> 4) * 3 + g) * 16 + (j & 15);
    float w = tile[tx][jl];
    unsigned short hi = f2bf(w);
    Whi[(size_t)dstRow * Hp + kb + tx] = hi;
    Wlo[(size_t)dstRow * Hp + kb + tx] = f2bf(w - bf2f(hi));
  }
}

// ---------------------------------------------------------------- h0 -> bf16 hi/lo ; zero barriers
__global__ void h0_kernel(const float* __restrict__ carry,
                          unsigned short* __restrict__ hhi,
                          unsigned short* __restrict__ hlo,
                          unsigned* __restrict__ bar) {
  int i = blockIdx.x * 256 + threadIdx.x;
  float h = carry[i];
  unsigned short hi = f2bf(h);
  hhi[i] = hi;
  hlo[i] = f2bf(h - bf2f(hi));
  if (i < 4 * 256) bar[i] = 0u;
}

// ---------------------------------------------------------------- persistent MFMA GRU scan
// 256 blocks x 256 threads (4 waves). block = (mb = blockIdx&3: 16 batches) x
// (jb = blockIdx>>2: 16 cols x 3 gates). Wave w owns K-quarter.
// 4 independent groups of 64 blocks (batches are independent recurrences).
// NO cache-wide fences: the h ping-pong + barrier counters are accessed only
// with agent-scope relaxed atomics (sc1 — write-through/read-through the
// coherence point). Weights/XV/tokens are normal cached loads -> L2 stays warm.
__global__ __launch_bounds__(256, 1) void gru_scan(
    const float* __restrict__ carry,
    float* __restrict__ ys,
    const unsigned short* __restrict__ Whi,
    const unsigned short* __restrict__ Wlo,
    const float* __restrict__ XV,
    const int* __restrict__ toks,
    const float* __restrict__ bhn,
    unsigned short* hhi,
    unsigned short* hlo,
    unsigned* bar) {
  __shared__ float part[3 * 4 * 64 * 4];   // [g][wave][lane][reg] = 12 KB
  __shared__ unsigned short hst[2][16][16]; // staged h tile for vectorized stores, 1 KB

  const int tid = threadIdx.x;
  const int wv = tid >> 6, lane = tid & 63;
  const int mb = blockIdx.x & 3, jb = blockIdx.x >> 2;
  const int col = lane & 15, kq = lane >> 4;

  unsigned* ctr = bar + mb * 256;          // group counter, 1 KB apart

  // B-frag base pointers (wave's K-quarter) — normal cached loads, L2-resident
  const int kbase = wv * 256 + kq * 8;
  const unsigned short* bhp[3];
  const unsigned short* blp[3];
  #pragma unroll
  for (int g = 0; g < 3; ++g) {
    const size_t rowoff = ((size_t)(jb * 3 + g) * 16 + col) * Hp + kbase;
    bhp[g] = Whi + rowoff;
    blp[g] = Wlo + rowoff;
  }

  // epilogue mapping: thread -> one output element (16x16 tile)
  const int erow = tid >> 4, ecol = tid & 15;
  const int eb = mb * 16 + erow;
  const int ej = jb * 16 + ecol;
  const int elane = (erow >> 2) * 16 + ecol;
  const int er = erow & 3;
  const float bhnv = bhn[ej];

  const size_t aBase = (size_t)(mb * 16 + col) * Hp + kbase;
  const size_t eOff = (size_t)eb * Hp + ej;

  // register-carried state
  float holdR = carry[eOff];
  int tok0 = toks[eb * Sp + 0];
  const float* xvp0 = XV + (size_t)tok0 * (3 * Hp) + ej;
  float xr = xvp0[0], xz = xvp0[Hp], xn = xvp0[2 * Hp];

  // store mapping: threads 0..127 each store one 8-B chunk (plane, row, quad)
  const int splane = tid >> 6;             // 0=hi, 1=lo (threads 0..127)
  const int srow = (tid >> 2) & 15;
  const int squad = tid & 3;
  const size_t sOff = (size_t)(mb * 16 + srow) * Hp + jb * 16 + squad * 4;

  for (int t = 0; t < Sp; ++t) {
    const unsigned short* hhiR = hhi + (size_t)(t & 1) * (Bp * Hp);
    const unsigned short* hloR = hlo + (size_t)(t & 1) * (Bp * Hp);
    unsigned short* hhiW = hhi + (size_t)((t + 1) & 1) * (Bp * Hp);
    unsigned short* hloW = hlo + (size_t)((t + 1) & 1) * (Bp * Hp);

    // A fragments: agent-coherent loads (the only barrier-dependent loads)
    s8v ah[8], al[8];
    #pragma unroll
    for (int c = 0; c < 8; ++c) {
      ah[c] = ald16(hhiR + aBase + (size_t)c * 32);
      al[c] = ald16(hloR + aBase + (size_t)c * 32);
    }

    // prefetch next step's token + XV gate values (independent of h)
    float xrN, xzN, xnN;
    {
      int tN = (t + 1 < Sp) ? (t + 1) : t;
      int tokN = toks[eb * Sp + tN];
      const float* xvpN = XV + (size_t)tokN * (3 * Hp) + ej;
      xrN = xvpN[0];
      xzN = xvpN[Hp];
      xnN = xvpN[2 * Hp];
    }

    f4v ar = {0.f, 0.f, 0.f, 0.f}, az = {0.f, 0.f, 0.f, 0.f}, an = {0.f, 0.f, 0.f, 0.f};
    #pragma unroll
    for (int c = 0; c < 8; ++c) {
      s8v b0 = *(const s8v*)(bhp[0] + c * 32);
      s8v b1 = *(const s8v*)(bhp[1] + c * 32);
      s8v b2 = *(const s8v*)(bhp[2] + c * 32);
      s8v l0 = *(const s8v*)(blp[0] + c * 32);
      s8v l1 = *(const s8v*)(blp[1] + c * 32);
      s8v l2 = *(const s8v*)(blp[2] + c * 32);
      ar = __builtin_amdgcn_mfma_f32_16x16x32_bf16(ah[c], b0, ar, 0, 0, 0);
      az = __builtin_amdgcn_mfma_f32_16x16x32_bf16(ah[c], b1, az, 0, 0, 0);
      an = __builtin_amdgcn_mfma_f32_16x16x32_bf16(ah[c], b2, an, 0, 0, 0);
      ar = __builtin_amdgcn_mfma_f32_16x16x32_bf16(al[c], b0, ar, 0, 0, 0);
      az = __builtin_amdgcn_mfma_f32_16x16x32_bf16(al[c], b1, az, 0, 0, 0);
      an = __builtin_amdgcn_mfma_f32_16x16x32_bf16(al[c], b2, an, 0, 0, 0);
      ar = __builtin_amdgcn_mfma_f32_16x16x32_bf16(ah[c], l0, ar, 0, 0, 0);
      az = __builtin_amdgcn_mfma_f32_16x16x32_bf16(ah[c], l1, az, 0, 0, 0);
      an = __builtin_amdgcn_mfma_f32_16x16x32_bf16(ah[c], l2, an, 0, 0, 0);
    }

    // cross-wave K reduction via LDS
    *(f4v*)&part[((0 * 4 + wv) * 64 + lane) * 4] = ar;
    *(f4v*)&part[((1 * 4 + wv) * 64 + lane) * 4] = az;
    *(f4v*)&part[((2 * 4 + wv) * 64 + lane) * 4] = an;
    __syncthreads();

    float sr = 0.f, sz = 0.f, sn = 0.f;
    #pragma unroll
    for (int w = 0; w < 4; ++w) {
      sr += part[((0 * 4 + w) * 64 + elane) * 4 + er];
      sz += part[((1 * 4 + w) * 64 + elane) * 4 + er];
      sn += part[((2 * 4 + w) * 64 + elane) * 4 + er];
    }

    float rg = 1.f / (1.f + expf(-(sr + xr)));
    float zg = 1.f / (1.f + expf(-(sz + xz)));
    float ng = tanhf(xn + rg * (sn + bhnv));
    float hnew = (1.f - zg) * ng + zg * holdR;

    __builtin_nontemporal_store(hnew, ys + (size_t)t * (Bp * Hp) + eOff);
    unsigned short hi16 = f2bf(hnew);
    hst[0][erow][ecol] = hi16;
    hst[1][erow][ecol] = f2bf(hnew - bf2f(hi16));

    holdR = hnew;
    xr = xrN; xz = xzN; xn = xnN;

    __syncthreads();
    // vectorized agent-coherent h stores (threads 0..127, 8 B each)
    if (tid < 128) {
      unsigned long long v = *(const unsigned long long*)&hst[splane][srow][squad * 4];
      ast8((splane ? hloW : hhiW) + sOff, v);
    }

    // ---- group barrier (64 blocks, monotonic counter, no cache fences) ----
    __threadfence_block();                // waitcnt drain per wave (no cache ops)
    __syncthreads();                      // all waves' stores retired
    if (tid == 0) {
      __hip_atomic_fetch_add(ctr, 1u, __ATOMIC_RELAXED, __HIP_MEMORY_SCOPE_AGENT);
      unsigned target = 64u * (unsigned)(t + 1);
      while (__hip_atomic_load(ctr, __ATOMIC_RELAXED, __HIP_MEMORY_SCOPE_AGENT) < target)
        __builtin_amdgcn_s_sleep(2);
    }
    __syncthreads();
  }
}

// ---------------------------------------------------------------- fused output denses
__global__ __launch_bounds__(256) void dense_kernel(
    const float* __restrict__ ys,   // [S][B][H]
    const float* __restrict__ Wh, const float* __restrict__ bh,
    const float* __restrict__ Wo, const float* __restrict__ bo,
    float* __restrict__ out) {      // logits at out + B*H
  __shared__ float hs[16][1032];
  __shared__ float hid[16][1032];
  int tid = threadIdx.x;
  int r0 = blockIdx.x * 16;
  int bq = r0 / Sp;        // constant within tile (S % 16 == 0)
  int s0 = r0 % Sp;

  for (int i = tid; i < 16 * 256; i += 256) {
    int m = i >> 8;
    int f = i & 255;
    float4 v = ((const float4*)(ys + (size_t)(s0 + m) * (Bp * Hp) + (size_t)bq * Hp))[f];
    ((float4*)&hs[m][0])[f] = v;
  }
  __syncthreads();

  float4 acc[16];
  float4 bh4 = ((const float4*)bh)[tid];
  #pragma unroll
  for (int m = 0; m < 16; ++m) acc[m] = bh4;
  for (int k = 0; k < Hp; ++k) {
    float4 w = ((const float4*)(Wh + (size_t)k * Hp))[tid];
    #pragma unroll
    for (int m = 0; m < 16; ++m) {
      float hv = hs[m][k];
      acc[m].x += hv * w.x;
      acc[m].y += hv * w.y;
      acc[m].z += hv * w.z;
      acc[m].w += hv * w.w;
    }
  }
  #pragma unroll
  for (int m = 0; m < 16; ++m) ((float4*)&hid[m][0])[tid] = acc[m];
  __syncthreads();

  int o = tid & (Op - 1);
  int half = tid >> 7;
  float lacc[8];
  float bov = bo[o];
  #pragma unroll
  for (int mm = 0; mm < 8; ++mm) lacc[mm] = bov;
  for (int k = 0; k < Hp; ++k) {
    float wo = Wo[(size_t)k * Op + o];
    #pragma unroll
    for (int mm = 0; mm < 8; ++mm) lacc[mm] += hid[half * 8 + mm][k] * wo;
  }
  float* lo = out + (size_t)Bp * Hp;
  #pragma unroll
  for (int mm = 0; mm < 8; ++mm) {
    int r = r0 + half * 8 + mm;
    lo[(size_t)r * Op + o] = lacc[mm];
  }
}

// ---------------------------------------------------------------- carry out
__global__ void carry_kernel(const float* __restrict__ ys, float* __restrict__ out) {
  int i = blockIdx.x * 256 + threadIdx.x;
  out[i] = ys[(size_t)(Sp - 1) * (Bp * Hp) + i];
}

extern "C" void kernel_launch(void* const* d_in, const int* in_sizes, int n_in,
                              void* d_out, int out_size, void* d_ws, size_t ws_size,
                              hipStream_t stream) {
  const int*   toks = (const int*)  d_in[0];
  const float* carry= (const float*)d_in[1];
  const float* emb  = (const float*)d_in[2];
  const float* Wir  = (const float*)d_in[3];
  const float* bir  = (const float*)d_in[4];
  const float* Whr  = (const float*)d_in[5];
  const float* Wiz  = (const float*)d_in[6];
  const float* biz  = (const float*)d_in[7];
  const float* Whz  = (const float*)d_in[8];
  const float* Win  = (const float*)d_in[9];
  const float* bin_ = (const float*)d_in[10];
  const float* Whn  = (const float*)d_in[11];
  const float* bhn  = (const float*)d_in[12];
  const float* Wh   = (const float*)d_in[13];
  const float* bh   = (const float*)d_in[14];
  const float* Wo   = (const float*)d_in[15];
  const float* bo   = (const float*)d_in[16];
  float* out = (float*)d_out;

  if (ws_size < WS_FLOATS * sizeof(float)) return;

  float* ws = (float*)d_ws;
  float* XV = ws + WS_XV;
  unsigned short* WhiP = (unsigned short*)(ws + WS_WHI);
  unsigned short* WloP = (unsigned short*)(ws + WS_WLO);
  unsigned short* hhi  = (unsigned short*)(ws + WS_HHI);
  unsigned short* hlo  = (unsigned short*)(ws + WS_HLO);
  float* ys = ws + WS_YS;
  unsigned* bar = (unsigned*)(ws + WS_BAR);

  // preps
  xv_kernel<<<dim3(12, Vp), 256, 0, stream>>>(emb, Wir, bir, Wiz, biz, Win, bin_, XV);
  wpack_kernel<<<dim3(Hp / 32, Hp / 32, 3), dim3(32, 8), 0, stream>>>(Whr, Whz, Whn, WhiP, WloP);
  h0_kernel<<<(Bp * Hp) / 256, 256, 0, stream>>>(carry, hhi, hlo, bar);

  // persistent cooperative MFMA scan (co-residency guarantee; own group barriers)
  {
    void* args[] = {(void*)&carry, (void*)&ys, (void*)&WhiP, (void*)&WloP,
                    (void*)&XV, (void*)&toks, (void*)&bhn,
                    (void*)&hhi, (void*)&hlo, (void*)&bar};
    hipLaunchCooperativeKernel((const void*)gru_scan, dim3(256), dim3(256),
                               args, 0, stream);
  }

  // outputs
  carry_kernel<<<(Bp * Hp) / 256, 256, 0, stream>>>(ys, out);
  dense_kernel<<<(Bp * Sp) / 16, 256, 0, stream>>>(ys, Wh, bh, Wo, bo, out);
}

// Round 7
// 4515.935 us; speedup vs baseline: 11.5960x; 1.2130x over previous
//
#include <hip/hip_runtime.h>
#include <hip/hip_cooperative_groups.h>
#include <math.h>

namespace cg = cooperative_groups;

#define Bp 64
#define Sp 512
#define Ep 128
#define Hp 1024
#define Vp 128
#define Op 128
#define BH (Bp * Hp)

typedef short s8v __attribute__((ext_vector_type(8)));
typedef float f4v __attribute__((ext_vector_type(4)));

// ws layout (float units):
//   XV   : Vp*3*Hp floats        x-side projections per vocab id (incl. input biases)
//   Whi  : 3*Hp*Hp ushort        scan bf16 hi weights, row = ((j>>4)*3+g)*16+(j&15), k-contig
//   Wlo  : 3*Hp*Hp ushort        scan bf16 lo residuals, same layout
//   ysH  : (Sp+1)*BH ushort      bf16 hi of h history; row 0 = h_init, row t+1 = h_t
//   hloP : 2*BH ushort           bf16 lo of h, ping-pong (recurrence accuracy only)
//   WhbH/WhbL : Hp*Hp ushort     dense Wh bf16 hi/lo, [n][k] k-contig
//   WobH/WobL : Op*Hp ushort     dense Wo bf16 hi/lo, [o][k] k-contig
//   bar  : 4*256 uints           per-group barrier counters (1 KB apart)
#define WS_XV    0
#define WS_WHI   (WS_XV + Vp*3*Hp)
#define WS_WLO   (WS_WHI + (3*Hp*Hp)/2)
#define WS_YSH   (WS_WLO + (3*Hp*Hp)/2)
#define WS_HLOP  (WS_YSH + ((size_t)(Sp+1)*BH)/2)
#define WS_WHBH  (WS_HLOP + (2*BH)/2)
#define WS_WHBL  (WS_WHBH + (Hp*Hp)/2)
#define WS_WOBH  (WS_WHBL + (Hp*Hp)/2)
#define WS_WOBL  (WS_WOBH + (Op*Hp)/2)
#define WS_BAR   (WS_WOBL + (Op*Hp)/2)
#define WS_FLOATS (WS_BAR + 4*256)

__device__ __forceinline__ unsigned short f2bf(float x) {
  union { float f; unsigned u; } v; v.f = x;
  unsigned r = v.u + 0x7fffu + ((v.u >> 16) & 1u);   // RNE
  return (unsigned short)(r >> 16);
}
__device__ __forceinline__ float bf2f(unsigned short h) {
  union { unsigned u; float f; } v; v.u = ((unsigned)h) << 16;
  return v.f;
}

// agent-coherent 16B load as two 8B relaxed atomics (sc1 — reads the coherence
// point; immune to stale per-XCD L2)
__device__ __forceinline__ s8v ald16(const unsigned short* p) {
  union { unsigned long long q[2]; s8v v; } u;
  const unsigned long long* qp = (const unsigned long long*)p;
  u.q[0] = __hip_atomic_load(qp,     __ATOMIC_RELAXED, __HIP_MEMORY_SCOPE_AGENT);
  u.q[1] = __hip_atomic_load(qp + 1, __ATOMIC_RELAXED, __HIP_MEMORY_SCOPE_AGENT);
  return u.v;
}
__device__ __forceinline__ void ast8(unsigned short* p, unsigned long long v) {
  __hip_atomic_store((unsigned long long*)p, v, __ATOMIC_RELAXED, __HIP_MEMORY_SCOPE_AGENT);
}

// ---------------------------------------------------------------- XV precompute
__global__ __launch_bounds__(256) void xv_kernel(
    const float* __restrict__ emb,
    const float* __restrict__ Wir, const float* __restrict__ bir,
    const float* __restrict__ Wiz, const float* __restrict__ biz,
    const float* __restrict__ Win, const float* __restrict__ bin_,
    float* __restrict__ XV) {
  int n = blockIdx.x * 256 + threadIdx.x;   // 0..3071
  int v = blockIdx.y;                        // 0..127
  int g = n >> 10;
  int j = n & (Hp - 1);
  const float* W = (g == 0) ? Wir : ((g == 1) ? Wiz : Win);
  const float* bias = (g == 0) ? bir : ((g == 1) ? biz : bin_);
  float acc = bias[j];
  const float* ev = emb + (size_t)v * Ep;
  for (int e = 0; e < Ep; ++e) acc += ev[e] * W[(size_t)e * Hp + j];
  XV[(size_t)v * (3 * Hp) + n] = acc;
}

// ---------------------------------------------------------------- scan weight pack (bf16 hi/lo)
__global__ void wpack_kernel(const float* __restrict__ Whr,
                             const float* __restrict__ Whz,
                             const float* __restrict__ Whn,
                             unsigned short* __restrict__ Whi,
                             unsigned short* __restrict__ Wlo) {
  __shared__ float tile[32][33];
  int g = blockIdx.z;
  const float* src = (g == 0) ? Whr : ((g == 1) ? Whz : Whn);
  int kb = blockIdx.x * 32;
  int jb32 = blockIdx.y * 32;
  int tx = threadIdx.x, ty = threadIdx.y;  // 32 x 8
  #pragma unroll
  for (int i = 0; i < 4; ++i)
    tile[ty + 8 * i][tx] = src[(size_t)(kb + ty + 8 * i) * Hp + (jb32 + tx)];
  __syncthreads();
  #pragma unroll
  for (int i = 0; i < 4; ++i) {
    int jl = ty + 8 * i;
    int j = jb32 + jl;
    int dstRow = ((j >> 4) * 3 + g) * 16 + (j & 15);
    float w = tile[tx][jl];
    unsigned short hi = f2bf(w);
    Whi[(size_t)dstRow * Hp + kb + tx] = hi;
    Wlo[(size_t)dstRow * Hp + kb + tx] = f2bf(w - bf2f(hi));
  }
}

// ---------------------------------------------------------------- generic transpose+split
// src [K][N] fp32 -> dhi/dlo [N][K] bf16
__global__ void tsplit_kernel(const float* __restrict__ src, int K, int N,
                              unsigned short* __restrict__ dhi,
                              unsigned short* __restrict__ dlo) {
  __shared__ float tile[32][33];
  int kb = blockIdx.x * 32, nb = blockIdx.y * 32;
  int tx = threadIdx.x, ty = threadIdx.y;  // 32 x 8
  #pragma unroll
  for (int i = 0; i < 4; ++i)
    tile[ty + 8 * i][tx] = src[(size_t)(kb + ty + 8 * i) * N + nb + tx];
  __syncthreads();
  #pragma unroll
  for (int i = 0; i < 4; ++i) {
    int nl = ty + 8 * i;
    float w = tile[tx][nl];
    unsigned short hi = f2bf(w);
    dhi[(size_t)(nb + nl) * K + kb + tx] = hi;
    dlo[(size_t)(nb + nl) * K + kb + tx] = f2bf(w - bf2f(hi));
  }
}

// ---------------------------------------------------------------- h0 -> bf16 hi/lo ; zero barriers
__global__ void h0_kernel(const float* __restrict__ carry,
                          unsigned short* __restrict__ ysH,
                          unsigned short* __restrict__ hloP,
                          unsigned* __restrict__ bar) {
  int i = blockIdx.x * 256 + threadIdx.x;
  float h = carry[i];
  unsigned short hi = f2bf(h);
  ysH[i] = hi;              // row 0 of history
  hloP[i] = f2bf(h - bf2f(hi));  // slot 0
  if (i < 4 * 256) bar[i] = 0u;
}

// ---------------------------------------------------------------- persistent MFMA GRU scan
// 256 blocks x 256 threads. mb = blk>>6 (16-batch tile), jb = blk&63 (16 cols).
// XCD-aware: XCD = blk%8 = jb%8 -> only 8 distinct jb per XCD -> weight set
// 1.6 MB/XCD, L2-resident. 4 independent groups of 64 blocks (one per mb),
// relaxed atomic counter barrier, no cache-wide fences. h hi-plane written
// into ysH history (doubles as dense/carry input); lo-plane ping-pongs.
__global__ __launch_bounds__(256, 1) void gru_scan(
    const float* __restrict__ carry,
    unsigned short* ysH,
    const unsigned short* __restrict__ Whi,
    const unsigned short* __restrict__ Wlo,
    const float* __restrict__ XV,
    const int* __restrict__ toks,
    const float* __restrict__ bhn,
    unsigned short* hloP,
    unsigned* bar) {
  __shared__ float part[3 * 4 * 64 * 4];    // [g][wave][lane][reg] = 12 KB
  __shared__ unsigned short hst[2][16][16]; // staged h tile (hi, lo), 1 KB

  const int tid = threadIdx.x;
  const int wv = tid >> 6, lane = tid & 63;
  const int mb = blockIdx.x >> 6, jb = blockIdx.x & 63;
  const int col = lane & 15, kq = lane >> 4;

  unsigned* ctr = bar + mb * 256;

  const int kbase = wv * 256 + kq * 8;
  const unsigned short* bhp[3];
  const unsigned short* blp[3];
  #pragma unroll
  for (int g = 0; g < 3; ++g) {
    const size_t rowoff = ((size_t)(jb * 3 + g) * 16 + col) * Hp + kbase;
    bhp[g] = Whi + rowoff;
    blp[g] = Wlo + rowoff;
  }

  // epilogue mapping: thread -> one output element (16x16 tile)
  const int erow = tid >> 4, ecol = tid & 15;
  const int eb = mb * 16 + erow;
  const int ej = jb * 16 + ecol;
  const int elane = (erow >> 2) * 16 + ecol;
  const int er = erow & 3;
  const float bhnv = bhn[ej];

  const size_t aBase = (size_t)(mb * 16 + col) * Hp + kbase;
  const size_t eOff = (size_t)eb * Hp + ej;

  float holdR = carry[eOff];
  int tok0 = toks[eb * Sp + 0];
  const float* xvp0 = XV + (size_t)tok0 * (3 * Hp) + ej;
  float xr = xvp0[0], xz = xvp0[Hp], xn = xvp0[2 * Hp];

  // store mapping: threads 0..127 -> one 8-B chunk (plane, row, quad)
  const int splane = tid >> 6;
  const int srow = (tid >> 2) & 15;
  const int squad = tid & 3;
  const size_t sOff = (size_t)(mb * 16 + srow) * Hp + jb * 16 + squad * 4;

  for (int t = 0; t < Sp; ++t) {
    const unsigned short* hhiR = ysH + (size_t)t * BH;         // history row t
    const unsigned short* hloR = hloP + (size_t)(t & 1) * BH;
    unsigned short* hhiW = ysH + (size_t)(t + 1) * BH;
    unsigned short* hloW = hloP + (size_t)((t + 1) & 1) * BH;

    // A fragments (agent-coherent loads — the only barrier-dependent loads)
    s8v ah[8], al[8];
    #pragma unroll
    for (int c = 0; c < 8; ++c) {
      ah[c] = ald16(hhiR + aBase + (size_t)c * 32);
      al[c] = ald16(hloR + aBase + (size_t)c * 32);
    }

    // prefetch next step's token + XV gate values (independent of h)
    float xrN, xzN, xnN;
    {
      int tN = (t + 1 < Sp) ? (t + 1) : t;
      int tokN = toks[eb * Sp + tN];
      const float* xvpN = XV + (size_t)tokN * (3 * Hp) + ej;
      xrN = xvpN[0];
      xzN = xvpN[Hp];
      xnN = xvpN[2 * Hp];
    }

    f4v ar = {0.f, 0.f, 0.f, 0.f}, az = {0.f, 0.f, 0.f, 0.f}, an = {0.f, 0.f, 0.f, 0.f};
    #pragma unroll
    for (int c = 0; c < 8; ++c) {
      s8v b0 = *(const s8v*)(bhp[0] + c * 32);
      s8v b1 = *(const s8v*)(bhp[1] + c * 32);
      s8v b2 = *(const s8v*)(bhp[2] + c * 32);
      s8v l0 = *(const s8v*)(blp[0] + c * 32);
      s8v l1 = *(const s8v*)(blp[1] + c * 32);
      s8v l2 = *(const s8v*)(blp[2] + c * 32);
      ar = __builtin_amdgcn_mfma_f32_16x16x32_bf16(ah[c], b0, ar, 0, 0, 0);
      az = __builtin_amdgcn_mfma_f32_16x16x32_bf16(ah[c], b1, az, 0, 0, 0);
      an = __builtin_amdgcn_mfma_f32_16x16x32_bf16(ah[c], b2, an, 0, 0, 0);
      ar = __builtin_amdgcn_mfma_f32_16x16x32_bf16(al[c], b0, ar, 0, 0, 0);
      az = __builtin_amdgcn_mfma_f32_16x16x32_bf16(al[c], b1, az, 0, 0, 0);
      an = __builtin_amdgcn_mfma_f32_16x16x32_bf16(al[c], b2, an, 0, 0, 0);
      ar = __builtin_amdgcn_mfma_f32_16x16x32_bf16(ah[c], l0, ar, 0, 0, 0);
      az = __builtin_amdgcn_mfma_f32_16x16x32_bf16(ah[c], l1, az, 0, 0, 0);
      an = __builtin_amdgcn_mfma_f32_16x16x32_bf16(ah[c], l2, an, 0, 0, 0);
    }

    // cross-wave K reduction via LDS
    *(f4v*)&part[((0 * 4 + wv) * 64 + lane) * 4] = ar;
    *(f4v*)&part[((1 * 4 + wv) * 64 + lane) * 4] = az;
    *(f4v*)&part[((2 * 4 + wv) * 64 + lane) * 4] = an;
    __syncthreads();

    float sr = 0.f, sz = 0.f, sn = 0.f;
    #pragma unroll
    for (int w = 0; w < 4; ++w) {
      sr += part[((0 * 4 + w) * 64 + elane) * 4 + er];
      sz += part[((1 * 4 + w) * 64 + elane) * 4 + er];
      sn += part[((2 * 4 + w) * 64 + elane) * 4 + er];
    }

    float rg = 1.f / (1.f + expf(-(sr + xr)));
    float zg = 1.f / (1.f + expf(-(sz + xz)));
    float ng = tanhf(xn + rg * (sn + bhnv));
    float hnew = (1.f - zg) * ng + zg * holdR;

    unsigned short hi16 = f2bf(hnew);
    hst[0][erow][ecol] = hi16;
    hst[1][erow][ecol] = f2bf(hnew - bf2f(hi16));

    holdR = hnew;
    xr = xrN; xz = xzN; xn = xnN;

    __syncthreads();
    // vectorized agent-coherent h stores (threads 0..127, 8 B each)
    if (tid < 128) {
      unsigned long long v = *(const unsigned long long*)&hst[splane][srow][squad * 4];
      ast8((splane ? hloW : hhiW) + sOff, v);
    }

    // ---- group barrier (64 blocks, monotonic counter, no cache fences) ----
    __threadfence_block();
    __syncthreads();
    if (tid == 0) {
      __hip_atomic_fetch_add(ctr, 1u, __ATOMIC_RELAXED, __HIP_MEMORY_SCOPE_AGENT);
      unsigned target = 64u * (unsigned)(t + 1);
      while (__hip_atomic_load(ctr, __ATOMIC_RELAXED, __HIP_MEMORY_SCOPE_AGENT) < target)
        __builtin_amdgcn_s_sleep(2);
    }
    __syncthreads();
  }
}

// ---------------------------------------------------------------- fused MFMA output denses
// block = 16 out rows (r = b*S + s), 4 waves. Pass1: hidden = h@Wh+bh with
// B hi/lo (weight-exact); hidden tile -> LDS (MFMA-A layout, bf16). Pass2:
// logits = hidden@Wo+bo. Hidden never touches HBM.
__global__ __launch_bounds__(256, 1) void dense_kernel(
    const unsigned short* __restrict__ ysH,   // [(S+1)][B][H] bf16 hi; rows 1..S = h_t
    const unsigned short* __restrict__ WhbH, const unsigned short* __restrict__ WhbL,
    const float* __restrict__ bh,
    const unsigned short* __restrict__ WobH, const unsigned short* __restrict__ WobL,
    const float* __restrict__ bo,
    float* __restrict__ out) {
  __shared__ unsigned short aHi[32 * 16 * 4 * 8];    // [kc][m][kq][8] = 32 KB
  __shared__ unsigned short hidBf[32 * 16 * 4 * 8];  // same layout, 32 KB

  const int tid = threadIdx.x;
  const int wv = tid >> 6, lane = tid & 63;
  const int col = lane & 15, kq = lane >> 4;
  const int r0 = blockIdx.x * 16;
  const int bq = r0 / Sp, s0 = r0 % Sp;   // S%16==0: bq constant in tile

  // stage A: 16 rows x 1024 bf16, re-laid for conflict-free frag reads
  for (int i = tid; i < 16 * 128; i += 256) {
    int m = i >> 7, c8 = i & 127;          // chunk of 8 shorts, k = c8*8
    int kc = c8 >> 2, kqi = c8 & 3;
    const uint4* src = (const uint4*)(ysH + ((size_t)(s0 + m + 1) * Bp + bq) * Hp) + c8;
    *(uint4*)&aHi[((kc * 16 + m) * 4 + kqi) * 8] = *src;
  }
  __syncthreads();

  // ---- pass 1: wave w covers n in [w*256, w*256+256) ----
  f4v acc[16];
  #pragma unroll
  for (int nt = 0; nt < 16; ++nt) acc[nt] = (f4v){0.f, 0.f, 0.f, 0.f};
  for (int kc = 0; kc < 32; ++kc) {
    s8v a = *(const s8v*)&aHi[(kc * 64 + col * 4 + kq) * 8];
    const size_t koff = (size_t)kc * 32 + kq * 8;
    #pragma unroll
    for (int nt = 0; nt < 16; ++nt) {
      int n = wv * 256 + nt * 16 + col;
      s8v bHi = *(const s8v*)(WhbH + (size_t)n * Hp + koff);
      s8v bLo = *(const s8v*)(WhbL + (size_t)n * Hp + koff);
      acc[nt] = __builtin_amdgcn_mfma_f32_16x16x32_bf16(a, bHi, acc[nt], 0, 0, 0);
      acc[nt] = __builtin_amdgcn_mfma_f32_16x16x32_bf16(a, bLo, acc[nt], 0, 0, 0);
    }
  }
  // epilogue: +bias, bf16, scatter into MFMA-A layout (k = hidden feature n)
  #pragma unroll
  for (int nt = 0; nt < 16; ++nt) {
    int n = wv * 256 + nt * 16 + col;
    float bias = bh[n];
    int kc = n >> 5, kqi = (n >> 3) & 3, ii = n & 7;
    #pragma unroll
    for (int r = 0; r < 4; ++r) {
      int m = kq * 4 + r;                  // C-layout: row = (lane>>4)*4 + reg
      hidBf[((kc * 16 + m) * 4 + kqi) * 8 + ii] = f2bf(acc[nt][r] + bias);
    }
  }
  __syncthreads();

  // ---- pass 2: wave w covers o-tiles {2w, 2w+1} ----
  f4v lacc[2];
  lacc[0] = (f4v){0.f, 0.f, 0.f, 0.f};
  lacc[1] = (f4v){0.f, 0.f, 0.f, 0.f};
  for (int kc = 0; kc < 32; ++kc) {
    s8v a = *(const s8v*)&hidBf[(kc * 64 + col * 4 + kq) * 8];
    const size_t koff = (size_t)kc * 32 + kq * 8;
    #pragma unroll
    for (int ot = 0; ot < 2; ++ot) {
      int o = (wv * 2 + ot) * 16 + col;
      s8v bHi = *(const s8v*)(WobH + (size_t)o * Hp + koff);
      s8v bLo = *(const s8v*)(WobL + (size_t)o * Hp + koff);
      lacc[ot] = __builtin_amdgcn_mfma_f32_16x16x32_bf16(a, bHi, lacc[ot], 0, 0, 0);
      lacc[ot] = __builtin_amdgcn_mfma_f32_16x16x32_bf16(a, bLo, lacc[ot], 0, 0, 0);
    }
  }
  float* lo = out + (size_t)Bp * Hp;
  #pragma unroll
  for (int ot = 0; ot < 2; ++ot) {
    int o = (wv * 2 + ot) * 16 + col;
    float bias = bo[o];
    #pragma unroll
    for (int r = 0; r < 4; ++r) {
      int m = kq * 4 + r;
      lo[(size_t)(r0 + m) * Op + o] = lacc[ot][r] + bias;
    }
  }
}

// ---------------------------------------------------------------- carry out (hi+lo reconstruct)
__global__ void carry_kernel(const unsigned short* __restrict__ ysH,
                             const unsigned short* __restrict__ hloP,
                             float* __restrict__ out) {
  int i = blockIdx.x * 256 + threadIdx.x;
  out[i] = bf2f(ysH[(size_t)Sp * BH + i]) + bf2f(hloP[(size_t)(Sp & 1) * BH + i]);
}

extern "C" void kernel_launch(void* const* d_in, const int* in_sizes, int n_in,
                              void* d_out, int out_size, void* d_ws, size_t ws_size,
                              hipStream_t stream) {
  const int*   toks = (const int*)  d_in[0];
  const float* carry= (const float*)d_in[1];
  const float* emb  = (const float*)d_in[2];
  const float* Wir  = (const float*)d_in[3];
  const float* bir  = (const float*)d_in[4];
  const float* Whr  = (const float*)d_in[5];
  const float* Wiz  = (const float*)d_in[6];
  const float* biz  = (const float*)d_in[7];
  const float* Whz  = (const float*)d_in[8];
  const float* Win  = (const float*)d_in[9];
  const float* bin_ = (const float*)d_in[10];
  const float* Whn  = (const float*)d_in[11];
  const float* bhn  = (const float*)d_in[12];
  const float* Wh   = (const float*)d_in[13];
  const float* bh   = (const float*)d_in[14];
  const float* Wo   = (const float*)d_in[15];
  const float* bo   = (const float*)d_in[16];
  float* out = (float*)d_out;

  if (ws_size < WS_FLOATS * sizeof(float)) return;

  float* ws = (float*)d_ws;
  float* XV = ws + WS_XV;
  unsigned short* WhiP = (unsigned short*)(ws + WS_WHI);
  unsigned short* WloP = (unsigned short*)(ws + WS_WLO);
  unsigned short* ysH  = (unsigned short*)(ws + WS_YSH);
  unsigned short* hloP = (unsigned short*)(ws + WS_HLOP);
  unsigned short* WhbH = (unsigned short*)(ws + WS_WHBH);
  unsigned short* WhbL = (unsigned short*)(ws + WS_WHBL);
  unsigned short* WobH = (unsigned short*)(ws + WS_WOBH);
  unsigned short* WobL = (unsigned short*)(ws + WS_WOBL);
  unsigned* bar = (unsigned*)(ws + WS_BAR);

  // preps
  xv_kernel<<<dim3(12, Vp), 256, 0, stream>>>(emb, Wir, bir, Wiz, biz, Win, bin_, XV);
  wpack_kernel<<<dim3(Hp / 32, Hp / 32, 3), dim3(32, 8), 0, stream>>>(Whr, Whz, Whn, WhiP, WloP);
  tsplit_kernel<<<dim3(Hp / 32, Hp / 32), dim3(32, 8), 0, stream>>>(Wh, Hp, Hp, WhbH, WhbL);
  tsplit_kernel<<<dim3(Hp / 32, Op / 32), dim3(32, 8), 0, stream>>>(Wo, Hp, Op, WobH, WobL);
  h0_kernel<<<BH / 256, 256, 0, stream>>>(carry, ysH, hloP, bar);

  // persistent cooperative MFMA scan
  {
    void* args[] = {(void*)&carry, (void*)&ysH, (void*)&WhiP, (void*)&WloP,
                    (void*)&XV, (void*)&toks, (void*)&bhn,
                    (void*)&hloP, (void*)&bar};
    hipLaunchCooperativeKernel((const void*)gru_scan, dim3(256), dim3(256),
                               args, 0, stream);
  }

  // outputs
  carry_kernel<<<BH / 256, 256, 0, stream>>>(ysH, hloP, out);
  dense_kernel<<<(Bp * Sp) / 16, 256, 0, stream>>>(ysH, WhbH, WhbL, bh, WobH, WobL, bo, out);
}